// Round 9
// baseline (65.994 us; speedup 1.0000x reference)
//
#include <hip/hip_runtime.h>
#include <math.h>

// CLIF spiking recurrence, [T=64, B=128, D=4096] fp32.
// One neuron per thread; 524288 threads = 8192 waves = 8 waves/SIMD (max).
//
// R9: defeat the compiler's load-sinking (R2/R7/R8 all showed VGPR=20 ->
// prefetch ring silently collapsed to 0-depth) with a hard scheduling fence:
// rolled ring r[PF]; each sub-step consumes r[k], stores, reissues
// r[k] = x[t+PF+k]; __builtin_amdgcn_sched_barrier(0) at the end of the
// outer body makes sinking those loads into the consuming iteration illegal
// -> 8 loads pinned in flight ~1600 cyc ahead (HBM-miss latency ~900 cyc;
// FETCH_SIZE shows ~half the input is HBM-served). Tail: clamped index
// (redundant L2-hot reloads of t=63, negligible).
//
// NUMERICS FROZEN (R1-R8: absmax 0.0). R5 form:
//   - state chain in f32, single-rounded __f*_rn ops, no contraction
//   - spike test (u >= 1.0f) == fl(u-1) >= 0 (Sterbenz)
//   - spike gating via select (spike in {0,1}) -> bit-identical to multiply
//   - sigmoid: f64, fp32 result correctly rounded (rel err ~1e-11):
//     magic-add rint, y = f*ln2, deg-9 Taylor Horner, exponent-bit 2^n,
//     recip = v_rcp_f32 seed + 1 f64 Newton.

#define T_STEPS 64
#define BD      (128 * 4096)   // 524288 neurons
#define PF      8              // ring depth / inner unroll

__device__ __forceinline__ float sigmoid_cr(float x) {
    const double SHIFT = 6755399441055744.0;     // 2^52 + 2^51
    double t  = (double)x * -1.4426950408889634; // -x * log2(e)
    double tn = t + SHIFT;                       // rint via magic add (RNE)
    int    n  = __double2loint(tn);              // low 32 bits = n (2's comp)
    double f  = t - (tn - SHIFT);                // f in [-0.5, 0.5]
    double y  = f * 0.6931471805599453;          // f * ln2, |y| <= 0.3466
    // e^y, degree-9 Taylor (Horner); trunc err ~9.7e-12 rel
    double p = 2.755731922398589e-6;             // 1/9!
    p = fma(p, y, 2.480158730158730e-5);         // 1/8!
    p = fma(p, y, 1.984126984126984e-4);         // 1/7!
    p = fma(p, y, 1.388888888888889e-3);         // 1/6!
    p = fma(p, y, 8.333333333333333e-3);         // 1/5!
    p = fma(p, y, 4.166666666666666e-2);         // 1/4!
    p = fma(p, y, 1.666666666666667e-1);         // 1/3!
    p = fma(p, y, 0.5);                          // 1/2!
    p = fma(p, y, 1.0);
    p = fma(p, y, 1.0);
    // scale by 2^n (n bounded ~[-20,20] for this data)
    double sc = __hiloint2double(0x3FF00000 + ((unsigned)n << 20), 0);
    double e  = p * sc;                          // e^{-x}
    double d  = 1.0 + e;
    // reciprocal: f32 rcp seed (err ~6e-8) + 1 f64 Newton -> err ~4e-15
    double r = (double)__builtin_amdgcn_rcpf((float)d);
    r = r * fma(-d, r, 2.0);
    return (float)r;
}

__device__ __forceinline__ float clif_step(float& u, float& m, float x) {
    // u = 0.5*u + x  (mul exact, one rounding in add)
    u = __fadd_rn(__fmul_rn(0.5f, u), x);
    bool spike = (u >= 1.0f);
    // m = m * sigmoid(0.5*u) + spike   (0.5f*u exact; +1 via select)
    float s1  = sigmoid_cr(__fmul_rn(0.5f, u));
    float ms1 = __fmul_rn(m, s1);
    float mn  = spike ? __fadd_rn(ms1, 1.0f) : ms1;
    // sm = sigmoid(m); carried as next m (in-place sigmoid_ semantics)
    float sm = sigmoid_cr(mn);
    // u = u - spike * (1 + sm)  (select form, bit-identical)
    u = spike ? __fsub_rn(u, __fadd_rn(1.0f, sm)) : u;
    m = sm;
    return spike ? 1.0f : 0.0f;
}

__global__ __launch_bounds__(256, 8) void clif_kernel(const float* __restrict__ x,
                                                      float* __restrict__ o) {
    int gid = blockIdx.x * blockDim.x + threadIdx.x;  // 0 .. BD-1
    const float* xp = x + gid;
    float*       op = o + gid;

    float u = 0.f, m = 0.f;

    // prime the ring: loads for t = 0..PF-1
    float r[PF];
    #pragma unroll
    for (int k = 0; k < PF; ++k)
        r[k] = xp[(size_t)k * BD];

    #pragma unroll 1
    for (int t = 0; t < T_STEPS; t += PF) {
        #pragma unroll
        for (int k = 0; k < PF; ++k) {
            float s = clif_step(u, m, r[k]);
            __builtin_nontemporal_store(s, op + (size_t)(t + k) * BD);
            // reissue slot k for step t+PF+k (clamped; tail reloads are
            // L2-hot and discarded)
            int idx = t + PF + k;
            idx = idx < T_STEPS ? idx : (T_STEPS - 1);
            r[k] = xp[(size_t)idx * BD];
        }
        // hard fence: loads above may NOT sink past this point (their
        // consumers are in the next iteration) -> ring stays 8 deep.
        __builtin_amdgcn_sched_barrier(0);
    }
}

extern "C" void kernel_launch(void* const* d_in, const int* in_sizes, int n_in,
                              void* d_out, int out_size, void* d_ws, size_t ws_size,
                              hipStream_t stream) {
    const float* x = (const float*)d_in[0];
    float* out = (float*)d_out;
    dim3 block(256);
    dim3 grid(BD / 256);  // 2048 blocks -> 8 blocks/CU -> 32 waves/CU (max)
    clif_kernel<<<grid, block, 0, stream>>>(x, out);
}

// Round 10
// 63.630 us; speedup vs baseline: 1.0372x; 1.0372x over previous
//
#include <hip/hip_runtime.h>
#include <math.h>

// CLIF spiking recurrence, [T=64, B=128, D=4096] fp32.
// One neuron per thread; 524288 threads = 8192 waves = 8 waves/SIMD (max).
// Structure = R8 (best timed: 64.5us). R10 = two exact-identity f64 trims:
//   (1) poly evaluates 2^f directly (coeffs ln2^k/k!) -> deletes y=f*ln2 mul.
//       deg-9 trunc err 6.9e-12 == precision class of passing R5/R8 (9.7e-12).
//   (2) (double)(0.5f*u)*(-log2e) == (double)u*(-0.5*log2e) bit-for-bit
//       (0.5f*u exact) -> deletes the f32 half-mul feeding sigmoid1.
//
// NUMERICS (R1-R9: absmax 0.0, 9 consecutive):
//   - state chain in f32, single-rounded __f*_rn ops, no contraction
//   - spike test (u >= 1.0f) == fl(u-1) >= 0 (Sterbenz)
//   - spike gating via select (spike in {0,1}) -> bit-identical to multiply
//   - sigmoid: f64, fp32 result correctly rounded (margin ~1e-11 vs
//     half-ulp 3e-8): magic-add rint, deg-9 2^f Horner, exponent-bit 2^n,
//     recip = v_rcp_f32 seed + 1 f64 Newton.

#define T_STEPS 64
#define BD      (128 * 4096)   // 524288 neurons
#define PF      8              // prefetch depth / unroll

// core: given t = -x*log2(e) (f64), return sigmoid(x) rounded to f32
__device__ __forceinline__ float sigmoid_core(double t) {
    const double SHIFT = 6755399441055744.0;     // 2^52 + 2^51
    double tn = t + SHIFT;                       // rint via magic add (RNE)
    int    n  = __double2loint(tn);              // n = rint(t), 2's comp
    double f  = t - (tn - SHIFT);                // f in [-0.5, 0.5]
    // 2^f, degree-9 Horner, coeffs ln2^k/k!; trunc err ~6.9e-12 rel
    double p = 1.01780860092397e-7;              // ln2^9/9!
    p = fma(p, f, 1.32154867901443094e-6);       // ln2^8/8!
    p = fma(p, f, 1.52527338040598403e-5);       // ln2^7/7!
    p = fma(p, f, 1.54035303933816099e-4);       // ln2^6/6!
    p = fma(p, f, 1.33335581464284434e-3);       // ln2^5/5!
    p = fma(p, f, 9.61812910762847716e-3);       // ln2^4/4!
    p = fma(p, f, 5.55041086648215930e-2);       // ln2^3/3!
    p = fma(p, f, 2.40226506959100712e-1);       // ln2^2/2!
    p = fma(p, f, 6.93147180559945286e-1);       // ln2
    p = fma(p, f, 1.0);
    // scale by 2^n (n bounded ~[-20,20] for this data)
    double sc = __hiloint2double(0x3FF00000 + ((unsigned)n << 20), 0);
    double e  = p * sc;                          // e^{-x}
    double d  = 1.0 + e;
    // reciprocal: f32 rcp seed (err ~6e-8) + 1 f64 Newton -> err ~4e-15
    double r = (double)__builtin_amdgcn_rcpf((float)d);
    r = r * fma(-d, r, 2.0);
    return (float)r;
}

__device__ __forceinline__ float clif_step(float& u, float& m, float x) {
    // u = 0.5*u + x  (mul exact, one rounding in add)
    u = __fadd_rn(__fmul_rn(0.5f, u), x);
    bool spike = (u >= 1.0f);
    // s1 = sigmoid(0.5f*u): 0.5f*u exact -> fold 0.5 into f64 constant
    float s1  = sigmoid_core((double)u * -0.7213475204444817);  // -0.5*log2(e)
    float ms1 = __fmul_rn(m, s1);
    float mn  = spike ? __fadd_rn(ms1, 1.0f) : ms1;
    // sm = sigmoid(mn); carried as next m (in-place sigmoid_ semantics)
    float sm = sigmoid_core((double)mn * -1.4426950408889634);  // -log2(e)
    // u = u - spike * (1 + sm)  (select form, bit-identical)
    u = spike ? __fsub_rn(u, __fadd_rn(1.0f, sm)) : u;
    m = sm;
    return spike ? 1.0f : 0.0f;
}

__global__ __launch_bounds__(256, 8) void clif_kernel(const float* __restrict__ x,
                                                      float* __restrict__ o) {
    int gid = blockIdx.x * blockDim.x + threadIdx.x;  // 0 .. BD-1
    const float* xp = x + gid;
    float*       op = o + gid;

    float u = 0.f, m = 0.f;

    float r[PF];
    #pragma unroll
    for (int k = 0; k < PF; ++k)
        r[k] = xp[(size_t)k * BD];

    #pragma unroll 1
    for (int t = 0; t < T_STEPS; t += PF) {
        float nx[PF];
        const bool more = (t + PF < T_STEPS);   // wave-uniform guard
        if (more) {
            #pragma unroll
            for (int k = 0; k < PF; ++k)
                nx[k] = xp[(size_t)(t + PF + k) * BD];
        }

        #pragma unroll
        for (int k = 0; k < PF; ++k) {
            float s = clif_step(u, m, r[k]);
            __builtin_nontemporal_store(s, op + (size_t)(t + k) * BD);
        }

        if (more) {
            #pragma unroll
            for (int k = 0; k < PF; ++k)
                r[k] = nx[k];
        }
    }
}

extern "C" void kernel_launch(void* const* d_in, const int* in_sizes, int n_in,
                              void* d_out, int out_size, void* d_ws, size_t ws_size,
                              hipStream_t stream) {
    const float* x = (const float*)d_in[0];
    float* out = (float*)d_out;
    dim3 block(256);
    dim3 grid(BD / 256);  // 2048 blocks -> 8 blocks/CU -> 32 waves/CU (max)
    clif_kernel<<<grid, block, 0, stream>>>(x, out);
}